// Round 9
// baseline (533.682 us; speedup 1.0000x reference)
//
#include <hip/hip_runtime.h>
#include <hip/hip_bf16.h>

#define NTOK 512
#define TJ 32
#define NHALF 8            // j-tiles per half-block (2 blocks per i)
#define EPSF 1e-5f
#define WS_STRIDE 4224     // per half-block: 128*32 ACC + 128 bias row-sums (floats)

typedef __attribute__((ext_vector_type(4))) float f32x4;
typedef __attribute__((ext_vector_type(8))) short bf16x8;
typedef __attribute__((ext_vector_type(4))) short bf16x4;

struct HL { short hi; short lo; };

__device__ __forceinline__ short f2bf(float x) {
  __hip_bfloat16 h = __float2bfloat16(x);
  return *reinterpret_cast<short*>(&h);
}
__device__ __forceinline__ float bf2f(short s) {
  unsigned int u = ((unsigned int)(unsigned short)s) << 16;
  return __uint_as_float(u);
}
// split x ~= hi + lo (hi RNE bf16, lo = bf16(x - hi)): ~17 mantissa bits combined
__device__ __forceinline__ HL splitbf(float x) {
  HL r;
  r.hi = f2bf(x);
  r.lo = f2bf(x - bf2f(r.hi));
  return r;
}

// Main-loop LDS (double-buffered, 64000 B) union'd with the epilogue block
// (disjoint lifetimes: epilogue runs only after all main-loop LDS use is done).
struct __align__(16) SMemMain {
  float f0s[2][32*17];     // [buf][j][f], stride 17
  float f1s[2][32*49];     // [buf][j][c*3+x], stride 49
  float rhs[2][96];        // [buf][j*3+x]
  float maskf[2][32];
  short rbfHL[2][32*40];   // [buf][j][k]: k<16 hi, k>=16 lo; 80B row stride
  short Hh[2][128*40];     // [buf][h][j] bf16 hi, stride 40
  short Hl[2][128*40];     // lo
};
union __align__(16) SMemU {
  SMemMain m;
  struct {
    float ACCs[128*33];
    float biasR[128];
    float part[512];
    float m00s[16], m10s[16], p01s[48], p11s[48], rawbs[48], nrms[16];
  } e;
};

// ONE kernel, 1024 blocks (i = bid>>1, j-half = bid&1), 512 threads = 8 waves.
// Partial phase identical to R6 (57 us, VGPR 60, no spill). After the partial
// dump each i's two blocks rendezvous via device-scope fence + atomic counter
// (split-K last-block pattern): first arrival exits, second arrival runs the
// epilogue in-place (LDS union). Removes the second launch (+gap) that made
// the two-kernel version a net bench loss (R5/R6: 183-184 vs R2's 179.8).
__global__ __launch_bounds__(512, 4) void tfn_fused(
    const float* __restrict__ f0,  const float* __restrict__ f1,
    const float* __restrict__ rbf, const float* __restrict__ rhat,
    const int*  __restrict__ mask,
    const float* __restrict__ w00a, const float* __restrict__ b00a,
    const float* __restrict__ w00b, const float* __restrict__ b00b,
    const float* __restrict__ w10a, const float* __restrict__ b10a,
    const float* __restrict__ w10b, const float* __restrict__ b10b,
    const float* __restrict__ w01a, const float* __restrict__ b01a,
    const float* __restrict__ w01b, const float* __restrict__ b01b,
    const float* __restrict__ w11a, const float* __restrict__ b11a,
    const float* __restrict__ w11b, const float* __restrict__ b11b,
    const float* __restrict__ g0, const float* __restrict__ be0,
    const float* __restrict__ g1, const float* __restrict__ be1,
    float* __restrict__ ws, int* __restrict__ cnt,
    float* __restrict__ out)
{
  __shared__ SMemU sm;
  __shared__ int arrival;
  const int bid = blockIdx.x;
  const int i = bid >> 1;
  const int jbase = (bid & 1) * (NHALF * TJ);
  const int t = threadIdx.x;
  const int w = t >> 6;
  const int lane = t & 63;
  const int col = lane & 15;
  const int quad = lane >> 4;

  // ---- per-wave WA B-frags: bw1 = [Whi | Whi], bw2 = [Wlo | 0] ----
  bf16x8 bw1, bw2;
  float bav;
  {
    const int h = w*16 + col;
    const float* wa = (w < 2) ? (w00a + h*16) : (w < 4) ? (w10a + (h-32)*16)
                    : (w < 6) ? (w01a + (h-64)*16) : (w11a + (h-96)*16);
    bav = (w < 2) ? b00a[h] : (w < 4) ? b10a[h-32] : (w < 6) ? b01a[h-64] : b11a[h-96];
    #pragma unroll
    for (int e = 0; e < 8; ++e) {
      HL s = splitbf(wa[(quad & 1)*8 + e]);
      bw1[e] = s.hi;
      bw2[e] = (quad < 2) ? s.lo : (short)0;
    }
  }

  // ---- per-lane LHS constants (wave-uniform branch selectors) ----
  int fdiv = 0, xrem = 0, cidx = 0;
  if (w >= 2 && w < 5) { const int idx = (w-2)*16 + col; fdiv = idx/3; xrem = idx - 3*fdiv; }
  if (w >= 5) cidx = (w-5)*16 + col;
  const int hb = (w == 0) ? 0 : (w == 1) ? 2 : (w < 5) ? 4 : 6;

  // f1 staging index precompute
  int f1q0, f1r0, f1q1, f1r1, f1q2, f1r2;
  { int a = t;        f1q0 = a/48; f1r0 = a - 48*f1q0; }
  { int a = t + 512;  f1q1 = a/48; f1r1 = a - 48*f1q1; }
  { int a = t + 1024; f1q2 = a/48; f1r2 = a - 48*f1q2; }
  const int jrow = t >> 4, jfeat = t & 15;

  // ---- prologue: load tile 0, stage into buf 0, prefetch tile 1 ----
  float pf_f0, pf_f1_0, pf_f1_1, pf_f1_2, pf_rh = 0.f, pf_rbf;
  int pf_mk = 0;
  {
    pf_f0   = f0[(jbase + jrow)*16 + jfeat];
    pf_f1_0 = f1[jbase*48 + t]; pf_f1_1 = f1[jbase*48 + t + 512]; pf_f1_2 = f1[jbase*48 + t + 1024];
    if (t < 96) pf_rh = rhat[((size_t)i*NTOK + jbase)*3 + t];
    if (t < 32) pf_mk = mask[(size_t)i*NTOK + jbase + t];
    pf_rbf  = rbf[((size_t)i*NTOK + jbase + jrow)*16 + jfeat];

    sm.m.f0s[0][jrow*17 + jfeat] = pf_f0;
    sm.m.f1s[0][f1q0*49 + f1r0] = pf_f1_0;
    sm.m.f1s[0][f1q1*49 + f1r1] = pf_f1_1;
    sm.m.f1s[0][f1q2*49 + f1r2] = pf_f1_2;
    if (t < 96) sm.m.rhs[0][t] = pf_rh;
    if (t < 32) sm.m.maskf[0][t] = pf_mk ? 1.f : 0.f;
    HL s = splitbf(pf_rbf);
    sm.m.rbfHL[0][jrow*40 + jfeat]      = s.hi;
    sm.m.rbfHL[0][jrow*40 + 16 + jfeat] = s.lo;

    const int j0 = jbase + TJ;
    pf_f0   = f0[(j0 + jrow)*16 + jfeat];
    pf_f1_0 = f1[j0*48 + t]; pf_f1_1 = f1[j0*48 + t + 512]; pf_f1_2 = f1[j0*48 + t + 1024];
    if (t < 96) pf_rh = rhat[((size_t)i*NTOK + j0)*3 + t];
    if (t < 32) pf_mk = mask[(size_t)i*NTOK + j0 + t];
    pf_rbf  = rbf[((size_t)i*NTOK + j0 + jrow)*16 + jfeat];
  }
  __syncthreads();   // staging buf0 visible

  f32x4 acc0 = {0.f,0.f,0.f,0.f}, acc1 = {0.f,0.f,0.f,0.f};
  float biasp = 0.f;
  const f32x4 zc = {0.f,0.f,0.f,0.f};
  bf16x8 afh, afl;   // phase-B A-frag, produced by LHS(t), consumed by B(t) next iter

  for (int tile = 0; tile < NHALF; ++tile) {
    const int cur = tile & 1, nxt = cur ^ 1;

    // ---- 1. stage tile+1 into buf nxt ----
    if (tile + 1 < NHALF) {
      sm.m.f0s[nxt][jrow*17 + jfeat] = pf_f0;
      sm.m.f1s[nxt][f1q0*49 + f1r0] = pf_f1_0;
      sm.m.f1s[nxt][f1q1*49 + f1r1] = pf_f1_1;
      sm.m.f1s[nxt][f1q2*49 + f1r2] = pf_f1_2;
      if (t < 96) sm.m.rhs[nxt][t] = pf_rh;
      if (t < 32) sm.m.maskf[nxt][t] = pf_mk ? 1.f : 0.f;
      HL s = splitbf(pf_rbf);
      sm.m.rbfHL[nxt][jrow*40 + jfeat]      = s.hi;
      sm.m.rbfHL[nxt][jrow*40 + 16 + jfeat] = s.lo;
    }

    // ---- 2. issue prefetch of tile+2 ----
    if (tile + 2 < NHALF) {
      const int j0 = jbase + (tile+2)*TJ;
      pf_f0   = f0[(j0 + jrow)*16 + jfeat];
      pf_f1_0 = f1[j0*48 + t]; pf_f1_1 = f1[j0*48 + t + 512]; pf_f1_2 = f1[j0*48 + t + 1024];
      if (t < 96) pf_rh = rhat[((size_t)i*NTOK + j0)*3 + t];
      if (t < 32) pf_mk = mask[(size_t)i*NTOK + j0 + t];
      pf_rbf  = rbf[((size_t)i*NTOK + j0 + jrow)*16 + jfeat];
    }

    // ---- 3. phase B for tile-1: ACC += L^T * H ----
    if (tile > 0) {
      const bf16x8 b0h = *(const bf16x8*)&sm.m.Hh[nxt][(hb*16+col)*40 + quad*8];
      const bf16x8 b0l = *(const bf16x8*)&sm.m.Hl[nxt][(hb*16+col)*40 + quad*8];
      const bf16x8 b1h = *(const bf16x8*)&sm.m.Hh[nxt][((hb+1)*16+col)*40 + quad*8];
      const bf16x8 b1l = *(const bf16x8*)&sm.m.Hl[nxt][((hb+1)*16+col)*40 + quad*8];
      acc0 = __builtin_amdgcn_mfma_f32_16x16x32_bf16(afl, b0h, acc0, 0, 0, 0);
      acc0 = __builtin_amdgcn_mfma_f32_16x16x32_bf16(afh, b0l, acc0, 0, 0, 0);
      acc0 = __builtin_amdgcn_mfma_f32_16x16x32_bf16(afh, b0h, acc0, 0, 0, 0);
      acc1 = __builtin_amdgcn_mfma_f32_16x16x32_bf16(afl, b1h, acc1, 0, 0, 0);
      acc1 = __builtin_amdgcn_mfma_f32_16x16x32_bf16(afh, b1l, acc1, 0, 0, 0);
      acc1 = __builtin_amdgcn_mfma_f32_16x16x32_bf16(afh, b1h, acc1, 0, 0, 0);
    }

    // ---- 4. phase A: H[cur] = silu(rbf @ WA^T + ba) ----
    {
      const bf16x8 a0 = *(const bf16x8*)&sm.m.rbfHL[cur][col*40 + quad*8];
      const bf16x8 a1 = *(const bf16x8*)&sm.m.rbfHL[cur][(16+col)*40 + quad*8];
      f32x4 d0 = __builtin_amdgcn_mfma_f32_16x16x32_bf16(a0, bw1, zc, 0, 0, 0);
      d0 = __builtin_amdgcn_mfma_f32_16x16x32_bf16(a0, bw2, d0, 0, 0, 0);
      f32x4 d1 = __builtin_amdgcn_mfma_f32_16x16x32_bf16(a1, bw1, zc, 0, 0, 0);
      d1 = __builtin_amdgcn_mfma_f32_16x16x32_bf16(a1, bw2, d1, 0, 0, 0);
      bf16x4 hv, lv;
      #pragma unroll
      for (int r = 0; r < 4; ++r) {
        float p = d0[r] + bav;
        float s = p * __builtin_amdgcn_rcpf(1.f + __expf(-p));
        HL e2 = splitbf(s); hv[r] = e2.hi; lv[r] = e2.lo;
      }
      *(bf16x4*)&sm.m.Hh[cur][(w*16+col)*40 + quad*4] = hv;
      *(bf16x4*)&sm.m.Hl[cur][(w*16+col)*40 + quad*4] = lv;
      #pragma unroll
      for (int r = 0; r < 4; ++r) {
        float p = d1[r] + bav;
        float s = p * __builtin_amdgcn_rcpf(1.f + __expf(-p));
        HL e2 = splitbf(s); hv[r] = e2.hi; lv[r] = e2.lo;
      }
      *(bf16x4*)&sm.m.Hh[cur][(w*16+col)*40 + 16 + quad*4] = hv;
      *(bf16x4*)&sm.m.Hl[cur][(w*16+col)*40 + 16 + quad*4] = lv;
    }

    // ---- 5. LHS: per-lane phase-B A-frag (consumed by B next iter) ----
    {
      const int jb = quad*8;
      float mkv[8];
      { const float4 mk0 = *(const float4*)&sm.m.maskf[cur][jb];
        const float4 mk1 = *(const float4*)&sm.m.maskf[cur][jb + 4];
        mkv[0]=mk0.x; mkv[1]=mk0.y; mkv[2]=mk0.z; mkv[3]=mk0.w;
        mkv[4]=mk1.x; mkv[5]=mk1.y; mkv[6]=mk1.z; mkv[7]=mk1.w; }
      float v[8];
      if (w == 0) {
        #pragma unroll
        for (int jj = 0; jj < 8; ++jj) v[jj] = mkv[jj] * sm.m.f0s[cur][(jb+jj)*17 + col];
      } else if (w < 5) {
        float rwin[24];
        #pragma unroll
        for (int q4 = 0; q4 < 6; ++q4) {
          const float4 rr = *(const float4*)&sm.m.rhs[cur][jb*3 + q4*4];
          rwin[q4*4+0]=rr.x; rwin[q4*4+1]=rr.y; rwin[q4*4+2]=rr.z; rwin[q4*4+3]=rr.w;
        }
        if (w == 1) {
          #pragma unroll
          for (int jj = 0; jj < 8; ++jj) {
            const float* fr = &sm.m.f1s[cur][(jb+jj)*49 + col*3];
            v[jj] = mkv[jj] * (rwin[jj*3+0]*fr[0] + rwin[jj*3+1]*fr[1] + rwin[jj*3+2]*fr[2]);
          }
        } else {
          #pragma unroll
          for (int jj = 0; jj < 8; ++jj)
            v[jj] = mkv[jj] * sm.m.f0s[cur][(jb+jj)*17 + fdiv] * rwin[jj*3 + xrem];
        }
      } else {
        #pragma unroll
        for (int jj = 0; jj < 8; ++jj) v[jj] = mkv[jj] * sm.m.f1s[cur][(jb+jj)*49 + cidx];
      }
      #pragma unroll
      for (int jj = 0; jj < 8; ++jj) {
        biasp += v[jj];
        HL s = splitbf(v[jj]);
        afh[jj] = s.hi; afl[jj] = s.lo;
      }
    }

    __syncthreads();   // H[cur] + staging[nxt] visible
  }

  // ---- final phase B for tile NHALF-1 ----
  {
    const int lb = (NHALF-1) & 1;
    const bf16x8 b0h = *(const bf16x8*)&sm.m.Hh[lb][(hb*16+col)*40 + quad*8];
    const bf16x8 b0l = *(const bf16x8*)&sm.m.Hl[lb][(hb*16+col)*40 + quad*8];
    const bf16x8 b1h = *(const bf16x8*)&sm.m.Hh[lb][((hb+1)*16+col)*40 + quad*8];
    const bf16x8 b1l = *(const bf16x8*)&sm.m.Hl[lb][((hb+1)*16+col)*40 + quad*8];
    acc0 = __builtin_amdgcn_mfma_f32_16x16x32_bf16(afl, b0h, acc0, 0, 0, 0);
    acc0 = __builtin_amdgcn_mfma_f32_16x16x32_bf16(afh, b0l, acc0, 0, 0, 0);
    acc0 = __builtin_amdgcn_mfma_f32_16x16x32_bf16(afh, b0h, acc0, 0, 0, 0);
    acc1 = __builtin_amdgcn_mfma_f32_16x16x32_bf16(afl, b1h, acc1, 0, 0, 0);
    acc1 = __builtin_amdgcn_mfma_f32_16x16x32_bf16(afh, b1l, acc1, 0, 0, 0);
    acc1 = __builtin_amdgcn_mfma_f32_16x16x32_bf16(afh, b1h, acc1, 0, 0, 0);
  }

  // ---- dump partial ACC + bias row-sums to workspace ----
  float* wsb = ws + (size_t)bid * WS_STRIDE;
  #pragma unroll
  for (int r = 0; r < 4; ++r) {
    const int m = w*16 + quad*4 + r;
    wsb[m*32 + col]      = acc0[r];
    wsb[m*32 + 16 + col] = acc1[r];
  }
  biasp += __shfl_xor(biasp, 16);
  biasp += __shfl_xor(biasp, 32);
  if (lane < 16) wsb[4096 + w*16 + col] = biasp;

  // ---- rendezvous: device-scope release, count arrivals ----
  __threadfence();                       // make ws writes visible at device scope
  if (t == 0) arrival = atomicAdd(&cnt[i], 1);
  __syncthreads();                       // arrival visible to all; main LDS reads done
  if (arrival == 0) return;              // first block exits, frees CU slot
  __threadfence();                       // acquire: see peer's ws data

  // ================= epilogue (second-arriving block only) =================
  const float* wa = ws + (size_t)(2*i) * WS_STRIDE;
  const float* wb = wa + WS_STRIDE;

  {
    const int row = t >> 2, cb = (t & 3) * 8;
    const float4 x0 = *(const float4*)&wa[row*32 + cb];
    const float4 x1 = *(const float4*)&wa[row*32 + cb + 4];
    const float4 y0 = *(const float4*)&wb[row*32 + cb];
    const float4 y1 = *(const float4*)&wb[row*32 + cb + 4];
    sm.e.ACCs[row*33 + cb + 0] = x0.x + y0.x;
    sm.e.ACCs[row*33 + cb + 1] = x0.y + y0.y;
    sm.e.ACCs[row*33 + cb + 2] = x0.z + y0.z;
    sm.e.ACCs[row*33 + cb + 3] = x0.w + y0.w;
    sm.e.ACCs[row*33 + cb + 4] = x1.x + y1.x;
    sm.e.ACCs[row*33 + cb + 5] = x1.y + y1.y;
    sm.e.ACCs[row*33 + cb + 6] = x1.z + y1.z;
    sm.e.ACCs[row*33 + cb + 7] = x1.w + y1.w;
    if (t < 128) sm.e.biasR[t] = wa[4096 + t] + wb[4096 + t];
  }
  __syncthreads();

  {
    const int tt = t & 127, half = t >> 7;   // 4-way split of the 16-long d loop
    float s = 0.f;
    if (tt < 16) {
      const int o = tt;
      #pragma unroll
      for (int dd = 0; dd < 4; ++dd) {
        const int d = half + dd*4;
        const float* wrow = w00b + (d*16 + o)*32;
        float ss = 0.f;
        #pragma unroll
        for (int hh = 0; hh < 32; ++hh) ss += wrow[hh] * sm.e.ACCs[d*33 + hh];
        s += ss + b00b[d*16 + o] * sm.e.biasR[d];
      }
    } else if (tt < 32) {
      const int o = tt - 16;
      #pragma unroll
      for (int dd = 0; dd < 4; ++dd) {
        const int c = half + dd*4, m = 16 + c;
        const float* wrow = w10b + (c*16 + o)*32;
        float ss = 0.f;
        #pragma unroll
        for (int hh = 0; hh < 32; ++hh) ss += wrow[hh] * sm.e.ACCs[m*33 + hh];
        s += ss + b10b[c*16 + o] * sm.e.biasR[m];
      }
    } else if (tt < 80) {
      const int idx = tt - 32, g = idx/3, x = idx - 3*g;
      #pragma unroll
      for (int dd = 0; dd < 4; ++dd) {
        const int f = half + dd*4, m = 32 + f*3 + x;
        const float* wrow = w01b + (f*16 + g)*32;
        float ss = 0.f;
        #pragma unroll
        for (int hh = 0; hh < 32; ++hh) ss += wrow[hh] * sm.e.ACCs[m*33 + hh];
        s += ss + b01b[f*16 + g] * sm.e.biasR[m];
      }
    } else {
      const int idx = tt - 80, g = idx/3, x = idx - 3*g;
      #pragma unroll
      for (int dd = 0; dd < 4; ++dd) {
        const int k = half + dd*4, m = 80 + k*3 + x;
        const float* wrow = w11b + (k*16 + g)*32;
        float ss = 0.f;
        #pragma unroll
        for (int hh = 0; hh < 32; ++hh) ss += wrow[hh] * sm.e.ACCs[m*33 + hh];
        s += ss + b11b[k*16 + g] * sm.e.biasR[m];
      }
    }
    sm.e.part[t] = s;
  }
  __syncthreads();

  if (t < 128) {
    const float s = sm.e.part[t] + sm.e.part[t+128] + sm.e.part[t+256] + sm.e.part[t+384];
    if (t < 16) sm.e.m00s[t] = s;
    else if (t < 32) sm.e.m10s[t-16] = s;
    else if (t < 80) sm.e.p01s[t-32] = s;
    else sm.e.p11s[t-80] = s;
  }
  __syncthreads();

  if (t < 16) {
    float vv = sm.e.m00s[t] + sm.e.m10s[t];
    float mu = 0.f;
    #pragma unroll
    for (int k = 0; k < 16; ++k) mu += sm.e.m00s[k] + sm.e.m10s[k];
    mu *= (1.f/16.f);
    float var = 0.f;
    #pragma unroll
    for (int k = 0; k < 16; ++k) { float d = sm.e.m00s[k] + sm.e.m10s[k] - mu; var += d*d; }
    var *= (1.f/16.f);
    out[(size_t)i*16 + t] = (vv - mu) * rsqrtf(var + EPSF) * g0[t] + be0[t];
    float r0v = sm.e.p01s[t*3+0] + sm.e.p11s[t*3+0];
    float r1v = sm.e.p01s[t*3+1] + sm.e.p11s[t*3+1];
    float r2v = sm.e.p01s[t*3+2] + sm.e.p11s[t*3+2];
    sm.e.rawbs[t*3+0] = r0v; sm.e.rawbs[t*3+1] = r1v; sm.e.rawbs[t*3+2] = r2v;
    sm.e.nrms[t] = fmaxf(sqrtf(r0v*r0v + r1v*r1v + r2v*r2v), 1e-8f);
  }
  __syncthreads();
  if (t < 16) {
    float mu = 0.f;
    #pragma unroll
    for (int k = 0; k < 16; ++k) mu += sm.e.nrms[k];
    mu *= (1.f/16.f);
    float var = 0.f;
    #pragma unroll
    for (int k = 0; k < 16; ++k) { float d = sm.e.nrms[k] - mu; var += d*d; }
    var *= (1.f/16.f);
    const float ln = (sm.e.nrms[t] - mu) * rsqrtf(var + EPSF) * g1[t] + be1[t];
    const float scale = ln / sm.e.nrms[t];
    const size_t base = (size_t)NTOK*16 + (size_t)i*48 + t*3;
    out[base+0] = sm.e.rawbs[t*3+0] * scale;
    out[base+1] = sm.e.rawbs[t*3+1] * scale;
    out[base+2] = sm.e.rawbs[t*3+2] * scale;
  }
}

extern "C" void kernel_launch(void* const* d_in, const int* in_sizes, int n_in,
                              void* d_out, int out_size, void* d_ws, size_t ws_size,
                              hipStream_t stream) {
  int idx_f0 = -1, idx_f1 = -1, idx_rbf = -1, idx_rhat = -1, idx_mask = -1;
  int wa_i[4], ba_i[4], wb_i[4], bb_i[4], g_i[4];
  int nwa = 0, nba = 0, nwb = 0, nbb = 0, ng = 0;
  for (int k = 0; k < n_in; ++k) {
    const int s = in_sizes[k];
    if      (s == 4194304) idx_rbf  = k;
    else if (s == 786432)  idx_rhat = k;
    else if (s == 262144)  idx_mask = k;
    else if (s == 24576)   idx_f1   = k;
    else if (s == 8192)    { if (idx_f0 < 0) idx_f0 = k; else if (nwb < 4) wb_i[nwb++] = k; }
    else if (s == 512)     { if (nwa < 4) wa_i[nwa++] = k; }
    else if (s == 32)      { if (nba < 4) ba_i[nba++] = k; }
    else if (s == 256)     { if (nbb < 4) bb_i[nbb++] = k; }
    else if (s == 16)      { if (ng  < 4) g_i[ng++]  = k; }
  }
  const bool ok = idx_f0 >= 0 && idx_f1 >= 0 && idx_rbf >= 0 && idx_rhat >= 0 &&
                  idx_mask >= 0 && nwa == 4 && nba == 4 && nwb == 4 && nbb == 4 && ng == 4;
  if (!ok) {
    idx_f0 = 1; idx_f1 = 2; idx_rbf = 3; idx_rhat = 4; idx_mask = 5;
    for (int q = 0; q < 4; ++q) {
      wa_i[q] = 6 + q*4; ba_i[q] = 7 + q*4; wb_i[q] = 8 + q*4; bb_i[q] = 9 + q*4;
      g_i[q] = 22 + q;
    }
  }
  float* ws = (float*)d_ws;
  int* cnt = (int*)((char*)d_ws + (size_t)1024 * WS_STRIDE * sizeof(float));
  hipMemsetAsync(cnt, 0, 512 * sizeof(int), stream);   // reset arrival counters (graph-safe)
  tfn_fused<<<1024, 512, 0, stream>>>(
      (const float*)d_in[idx_f0],  (const float*)d_in[idx_f1],
      (const float*)d_in[idx_rbf], (const float*)d_in[idx_rhat],
      (const int*)d_in[idx_mask],
      (const float*)d_in[wa_i[0]], (const float*)d_in[ba_i[0]],
      (const float*)d_in[wb_i[0]], (const float*)d_in[bb_i[0]],
      (const float*)d_in[wa_i[1]], (const float*)d_in[ba_i[1]],
      (const float*)d_in[wb_i[1]], (const float*)d_in[bb_i[1]],
      (const float*)d_in[wa_i[2]], (const float*)d_in[ba_i[2]],
      (const float*)d_in[wb_i[2]], (const float*)d_in[bb_i[2]],
      (const float*)d_in[wa_i[3]], (const float*)d_in[ba_i[3]],
      (const float*)d_in[wb_i[3]], (const float*)d_in[bb_i[3]],
      (const float*)d_in[g_i[0]], (const float*)d_in[g_i[1]],
      (const float*)d_in[g_i[2]], (const float*)d_in[g_i[3]],
      ws, cnt, (float*)d_out);
}

// Round 10
// 179.193 us; speedup vs baseline: 2.9783x; 2.9783x over previous
//
#include <hip/hip_runtime.h>
#include <hip/hip_bf16.h>

#define NTOK 512
#define TJ 32
#define NHALF 8            // j-tiles per half (waves 0-7: j<256, waves 8-15: j>=256)
#define EPSF 1e-5f

typedef __attribute__((ext_vector_type(4))) float f32x4;
typedef __attribute__((ext_vector_type(8))) short bf16x8;
typedef __attribute__((ext_vector_type(4))) short bf16x4;

struct HL { short hi; short lo; };

__device__ __forceinline__ short f2bf(float x) {
  __hip_bfloat16 h = __float2bfloat16(x);
  return *reinterpret_cast<short*>(&h);
}
__device__ __forceinline__ float bf2f(short s) {
  unsigned int u = ((unsigned int)(unsigned short)s) << 16;
  return __uint_as_float(u);
}
// split x ~= hi + lo (hi RNE bf16, lo = bf16(x - hi)): ~17 mantissa bits combined
__device__ __forceinline__ HL splitbf(float x) {
  HL r;
  r.hi = f2bf(x);
  r.lo = f2bf(x - bf2f(r.hi));
  return r;
}

// Per-half main-loop LDS (single-buffered R5 structure, 32000 B each).
struct __align__(16) SMemHalf {
  float f0s[32*17];      // [j][f], stride 17
  float f1s[32*49];      // [j][c*3+x], stride 49
  float rhs[96];         // [j*3+x]
  float maskf[32];
  short rbfHL[32*40];    // [j][k]: k<16 hi, k>=16 lo; 80B row stride
  short Hh[128*40];      // [h][j] bf16 hi, stride 40
  short Hl[128*40];      // lo
};
union __align__(16) SMemU {
  SMemHalf h[2];         // 64000 B main
  struct {               // epilogue region (disjoint lifetime; ~22 KB)
    float ACCs[128*33];
    float biasR[128];
    float part[1024];
    float m00s[16], m10s[16], p01s[48], p11s[48], rawbs[48], nrms[16];
  } e;
};

// ONE kernel, 512 blocks (one per i), 1024 threads = 16 waves.
// In-block j-split: half = t>>9 owns 8 j-tiles; each half runs the R5-verified
// 2-barrier loop in its own LDS region (barriers align: same tile count).
// ACC merge + epilogue are intra-block (plain __syncthreads) -- NO device
// fences, NO workspace. R9 showed __threadfence rendezvous costs ~380 us
// (per-XCD L2 writeback serialization); this removes it entirely, plus the
// second launch that made R5/R6 a net bench loss.
// launch_bounds(1024,4): 128-reg budget (R5: 60 VGPR, no spill). 16 waves =
// 4/SIMD = the VGPR-imposed residency -- geometry unchanged vs R5.
__global__ __launch_bounds__(1024, 4) void tfn_kernel(
    const float* __restrict__ f0,  const float* __restrict__ f1,
    const float* __restrict__ rbf, const float* __restrict__ rhat,
    const int*  __restrict__ mask,
    const float* __restrict__ w00a, const float* __restrict__ b00a,
    const float* __restrict__ w00b, const float* __restrict__ b00b,
    const float* __restrict__ w10a, const float* __restrict__ b10a,
    const float* __restrict__ w10b, const float* __restrict__ b10b,
    const float* __restrict__ w01a, const float* __restrict__ b01a,
    const float* __restrict__ w01b, const float* __restrict__ b01b,
    const float* __restrict__ w11a, const float* __restrict__ b11a,
    const float* __restrict__ w11b, const float* __restrict__ b11b,
    const float* __restrict__ g0, const float* __restrict__ be0,
    const float* __restrict__ g1, const float* __restrict__ be1,
    float* __restrict__ out)
{
  __shared__ SMemU sm;
  const int i = blockIdx.x;
  const int t = threadIdx.x;          // 0..1023
  const int half = t >> 9;            // j-half this thread works on
  const int th = t & 511;             // thread id within half
  const int w8 = th >> 6;             // wave id within half, 0..7
  const int lane = t & 63;
  const int col = lane & 15;
  const int quad = lane >> 4;
  const int jbase = half * (NHALF * TJ);
  SMemHalf* smh = &sm.h[half];

  // ---- per-wave WA B-frags: bw1 = [Whi | Whi], bw2 = [Wlo | 0] ----
  bf16x8 bw1, bw2;
  float bav;
  {
    const int h = w8*16 + col;
    const float* wa = (w8 < 2) ? (w00a + h*16) : (w8 < 4) ? (w10a + (h-32)*16)
                    : (w8 < 6) ? (w01a + (h-64)*16) : (w11a + (h-96)*16);
    bav = (w8 < 2) ? b00a[h] : (w8 < 4) ? b10a[h-32] : (w8 < 6) ? b01a[h-64] : b11a[h-96];
    #pragma unroll
    for (int e = 0; e < 8; ++e) {
      HL s = splitbf(wa[(quad & 1)*8 + e]);
      bw1[e] = s.hi;
      bw2[e] = (quad < 2) ? s.lo : (short)0;
    }
  }

  // ---- per-lane LHS constants (wave-uniform branch selectors) ----
  int fdiv = 0, xrem = 0, cidx = 0;
  if (w8 >= 2 && w8 < 5) { const int idx = (w8-2)*16 + col; fdiv = idx/3; xrem = idx - 3*fdiv; }
  if (w8 >= 5) cidx = (w8-5)*16 + col;
  const int hb = (w8 == 0) ? 0 : (w8 == 1) ? 2 : (w8 < 5) ? 4 : 6;

  // f1 staging index precompute (within-half)
  int f1q0, f1r0, f1q1, f1r1, f1q2, f1r2;
  { int a = th;        f1q0 = a/48; f1r0 = a - 48*f1q0; }
  { int a = th + 512;  f1q1 = a/48; f1r1 = a - 48*f1q1; }
  { int a = th + 1024; f1q2 = a/48; f1r2 = a - 48*f1q2; }
  const int jrow = th >> 4, jfeat = th & 15;

  // ---- prefetch tile 0 of this half ----
  float pf_f0, pf_f1_0, pf_f1_1, pf_f1_2, pf_rh = 0.f, pf_rbf;
  int pf_mk = 0;
  {
    pf_f0   = f0[(jbase + jrow)*16 + jfeat];
    pf_f1_0 = f1[jbase*48 + th]; pf_f1_1 = f1[jbase*48 + th + 512]; pf_f1_2 = f1[jbase*48 + th + 1024];
    if (th < 96) pf_rh = rhat[((size_t)i*NTOK + jbase)*3 + th];
    if (th < 32) pf_mk = mask[(size_t)i*NTOK + jbase + th];
    pf_rbf  = rbf[((size_t)i*NTOK + jbase + jrow)*16 + jfeat];
  }

  f32x4 acc0 = {0.f,0.f,0.f,0.f}, acc1 = {0.f,0.f,0.f,0.f};
  float biasp = 0.f;
  const f32x4 zc = {0.f,0.f,0.f,0.f};

  for (int tile = 0; tile < NHALF; ++tile) {
    // ---- stage regs -> this half's LDS ----
    smh->f0s[jrow*17 + jfeat] = pf_f0;
    smh->f1s[f1q0*49 + f1r0] = pf_f1_0;
    smh->f1s[f1q1*49 + f1r1] = pf_f1_1;
    smh->f1s[f1q2*49 + f1r2] = pf_f1_2;
    if (th < 96) smh->rhs[th] = pf_rh;
    if (th < 32) smh->maskf[th] = pf_mk ? 1.f : 0.f;
    { HL s = splitbf(pf_rbf);
      smh->rbfHL[jrow*40 + jfeat]      = s.hi;
      smh->rbfHL[jrow*40 + 16 + jfeat] = s.lo; }
    __syncthreads();   // staging visible (both halves in lockstep)

    // ---- prefetch tile+1 ----
    if (tile + 1 < NHALF) {
      const int j0 = jbase + (tile+1)*TJ;
      pf_f0   = f0[(j0 + jrow)*16 + jfeat];
      pf_f1_0 = f1[j0*48 + th]; pf_f1_1 = f1[j0*48 + th + 512]; pf_f1_2 = f1[j0*48 + th + 1024];
      if (th < 96) pf_rh = rhat[((size_t)i*NTOK + j0)*3 + th];
      if (th < 32) pf_mk = mask[(size_t)i*NTOK + j0 + th];
      pf_rbf  = rbf[((size_t)i*NTOK + j0 + jrow)*16 + jfeat];
    }

    // ---- phase A: H = silu(rbf @ WA^T + ba) ----
    {
      const bf16x8 a0 = *(const bf16x8*)&smh->rbfHL[col*40 + quad*8];
      const bf16x8 a1 = *(const bf16x8*)&smh->rbfHL[(16+col)*40 + quad*8];
      f32x4 d0 = __builtin_amdgcn_mfma_f32_16x16x32_bf16(a0, bw1, zc, 0, 0, 0);
      d0 = __builtin_amdgcn_mfma_f32_16x16x32_bf16(a0, bw2, d0, 0, 0, 0);
      f32x4 d1 = __builtin_amdgcn_mfma_f32_16x16x32_bf16(a1, bw1, zc, 0, 0, 0);
      d1 = __builtin_amdgcn_mfma_f32_16x16x32_bf16(a1, bw2, d1, 0, 0, 0);
      bf16x4 hv, lv;
      #pragma unroll
      for (int r = 0; r < 4; ++r) {
        float p = d0[r] + bav;
        float s = p * __builtin_amdgcn_rcpf(1.f + __expf(-p));
        HL e2 = splitbf(s); hv[r] = e2.hi; lv[r] = e2.lo;
      }
      *(bf16x4*)&smh->Hh[(w8*16+col)*40 + quad*4] = hv;
      *(bf16x4*)&smh->Hl[(w8*16+col)*40 + quad*4] = lv;
      #pragma unroll
      for (int r = 0; r < 4; ++r) {
        float p = d1[r] + bav;
        float s = p * __builtin_amdgcn_rcpf(1.f + __expf(-p));
        HL e2 = splitbf(s); hv[r] = e2.hi; lv[r] = e2.lo;
      }
      *(bf16x4*)&smh->Hh[(w8*16+col)*40 + 16 + quad*4] = hv;
      *(bf16x4*)&smh->Hl[(w8*16+col)*40 + 16 + quad*4] = lv;
    }

    // ---- LHS: per-lane phase-B A-frag (no LDS round-trip) ----
    bf16x8 afh, afl;
    {
      const int jb = quad*8;
      float mkv[8];
      { const float4 mk0 = *(const float4*)&smh->maskf[jb];
        const float4 mk1 = *(const float4*)&smh->maskf[jb + 4];
        mkv[0]=mk0.x; mkv[1]=mk0.y; mkv[2]=mk0.z; mkv[3]=mk0.w;
        mkv[4]=mk1.x; mkv[5]=mk1.y; mkv[6]=mk1.z; mkv[7]=mk1.w; }
      float v[8];
      if (w8 == 0) {
        #pragma unroll
        for (int jj = 0; jj < 8; ++jj) v[jj] = mkv[jj] * smh->f0s[(jb+jj)*17 + col];
      } else if (w8 < 5) {
        float rwin[24];
        #pragma unroll
        for (int q4 = 0; q4 < 6; ++q4) {
          const float4 rr = *(const float4*)&smh->rhs[jb*3 + q4*4];
          rwin[q4*4+0]=rr.x; rwin[q4*4+1]=rr.y; rwin[q4*4+2]=rr.z; rwin[q4*4+3]=rr.w;
        }
        if (w8 == 1) {
          #pragma unroll
          for (int jj = 0; jj < 8; ++jj) {
            const float* fr = &smh->f1s[(jb+jj)*49 + col*3];
            v[jj] = mkv[jj] * (rwin[jj*3+0]*fr[0] + rwin[jj*3+1]*fr[1] + rwin[jj*3+2]*fr[2]);
          }
        } else {
          #pragma unroll
          for (int jj = 0; jj < 8; ++jj)
            v[jj] = mkv[jj] * smh->f0s[(jb+jj)*17 + fdiv] * rwin[jj*3 + xrem];
        }
      } else {
        #pragma unroll
        for (int jj = 0; jj < 8; ++jj) v[jj] = mkv[jj] * smh->f1s[(jb+jj)*49 + cidx];
      }
      #pragma unroll
      for (int jj = 0; jj < 8; ++jj) {
        biasp += v[jj];
        HL s = splitbf(v[jj]);
        afh[jj] = s.hi; afl[jj] = s.lo;
      }
    }
    __syncthreads();   // H visible; staging fully consumed

    // ---- phase B: ACC += L^T * H ----
    {
      const bf16x8 b0h = *(const bf16x8*)&smh->Hh[(hb*16+col)*40 + quad*8];
      const bf16x8 b0l = *(const bf16x8*)&smh->Hl[(hb*16+col)*40 + quad*8];
      const bf16x8 b1h = *(const bf16x8*)&smh->Hh[((hb+1)*16+col)*40 + quad*8];
      const bf16x8 b1l = *(const bf16x8*)&smh->Hl[((hb+1)*16+col)*40 + quad*8];
      acc0 = __builtin_amdgcn_mfma_f32_16x16x32_bf16(afl, b0h, acc0, 0, 0, 0);
      acc0 = __builtin_amdgcn_mfma_f32_16x16x32_bf16(afh, b0l, acc0, 0, 0, 0);
      acc0 = __builtin_amdgcn_mfma_f32_16x16x32_bf16(afh, b0h, acc0, 0, 0, 0);
      acc1 = __builtin_amdgcn_mfma_f32_16x16x32_bf16(afl, b1h, acc1, 0, 0, 0);
      acc1 = __builtin_amdgcn_mfma_f32_16x16x32_bf16(afh, b1l, acc1, 0, 0, 0);
      acc1 = __builtin_amdgcn_mfma_f32_16x16x32_bf16(afh, b1h, acc1, 0, 0, 0);
    }
  }

  __syncthreads();   // all main-loop LDS reads done -> union region reusable

  // ---- merge halves: half 0 writes, half 1 accumulates ----
  biasp += __shfl_xor(biasp, 16);
  biasp += __shfl_xor(biasp, 32);
  if (half == 0) {
    #pragma unroll
    for (int r = 0; r < 4; ++r) {
      sm.e.ACCs[(w8*16 + quad*4 + r)*33 + col]      = acc0[r];
      sm.e.ACCs[(w8*16 + quad*4 + r)*33 + 16 + col] = acc1[r];
    }
    if (lane < 16) sm.e.biasR[w8*16 + col] = biasp;
  }
  __syncthreads();
  if (half == 1) {
    #pragma unroll
    for (int r = 0; r < 4; ++r) {
      sm.e.ACCs[(w8*16 + quad*4 + r)*33 + col]      += acc0[r];
      sm.e.ACCs[(w8*16 + quad*4 + r)*33 + 16 + col] += acc1[r];
    }
    if (lane < 16) sm.e.biasR[w8*16 + col] += biasp;
  }
  __syncthreads();

  // ---- epilogue: second-layer contraction, 8-way split of the 16-long d loop ----
  {
    const int tt = t & 127, oct = t >> 7;   // oct 0..7
    float s = 0.f;
    if (tt < 16) {
      const int o = tt;
      #pragma unroll
      for (int dd = 0; dd < 2; ++dd) {
        const int d = oct + dd*8;
        const float* wrow = w00b + (d*16 + o)*32;
        float ss = 0.f;
        #pragma unroll
        for (int hh = 0; hh < 32; ++hh) ss += wrow[hh] * sm.e.ACCs[d*33 + hh];
        s += ss + b00b[d*16 + o] * sm.e.biasR[d];
      }
    } else if (tt < 32) {
      const int o = tt - 16;
      #pragma unroll
      for (int dd = 0; dd < 2; ++dd) {
        const int c = oct + dd*8, m = 16 + c;
        const float* wrow = w10b + (c*16 + o)*32;
        float ss = 0.f;
        #pragma unroll
        for (int hh = 0; hh < 32; ++hh) ss += wrow[hh] * sm.e.ACCs[m*33 + hh];
        s += ss + b10b[c*16 + o] * sm.e.biasR[m];
      }
    } else if (tt < 80) {
      const int idx = tt - 32, g = idx/3, x = idx - 3*g;
      #pragma unroll
      for (int dd = 0; dd < 2; ++dd) {
        const int f = oct + dd*8, m = 32 + f*3 + x;
        const float* wrow = w01b + (f*16 + g)*32;
        float ss = 0.f;
        #pragma unroll
        for (int hh = 0; hh < 32; ++hh) ss += wrow[hh] * sm.e.ACCs[m*33 + hh];
        s += ss + b01b[f*16 + g] * sm.e.biasR[m];
      }
    } else {
      const int idx = tt - 80, g = idx/3, x = idx - 3*g;
      #pragma unroll
      for (int dd = 0; dd < 2; ++dd) {
        const int k = oct + dd*8, m = 80 + k*3 + x;
        const float* wrow = w11b + (k*16 + g)*32;
        float ss = 0.f;
        #pragma unroll
        for (int hh = 0; hh < 32; ++hh) ss += wrow[hh] * sm.e.ACCs[m*33 + hh];
        s += ss + b11b[k*16 + g] * sm.e.biasR[m];
      }
    }
    sm.e.part[t] = s;
  }
  __syncthreads();

  if (t < 128) {
    float s = 0.f;
    #pragma unroll
    for (int k = 0; k < 8; ++k) s += sm.e.part[t + 128*k];
    if (t < 16) sm.e.m00s[t] = s;
    else if (t < 32) sm.e.m10s[t-16] = s;
    else if (t < 80) sm.e.p01s[t-32] = s;
    else sm.e.p11s[t-80] = s;
  }
  __syncthreads();

  if (t < 16) {
    float vv = sm.e.m00s[t] + sm.e.m10s[t];
    float mu = 0.f;
    #pragma unroll
    for (int k = 0; k < 16; ++k) mu += sm.e.m00s[k] + sm.e.m10s[k];
    mu *= (1.f/16.f);
    float var = 0.f;
    #pragma unroll
    for (int k = 0; k < 16; ++k) { float d = sm.e.m00s[k] + sm.e.m10s[k] - mu; var += d*d; }
    var *= (1.f/16.f);
    out[(size_t)i*16 + t] = (vv - mu) * rsqrtf(var + EPSF) * g0[t] + be0[t];
    float r0v = sm.e.p01s[t*3+0] + sm.e.p11s[t*3+0];
    float r1v = sm.e.p01s[t*3+1] + sm.e.p11s[t*3+1];
    float r2v = sm.e.p01s[t*3+2] + sm.e.p11s[t*3+2];
    sm.e.rawbs[t*3+0] = r0v; sm.e.rawbs[t*3+1] = r1v; sm.e.rawbs[t*3+2] = r2v;
    sm.e.nrms[t] = fmaxf(sqrtf(r0v*r0v + r1v*r1v + r2v*r2v), 1e-8f);
  }
  __syncthreads();
  if (t < 16) {
    float mu = 0.f;
    #pragma unroll
    for (int k = 0; k < 16; ++k) mu += sm.e.nrms[k];
    mu *= (1.f/16.f);
    float var = 0.f;
    #pragma unroll
    for (int k = 0; k < 16; ++k) { float d = sm.e.nrms[k] - mu; var += d*d; }
    var *= (1.f/16.f);
    const float ln = (sm.e.nrms[t] - mu) * rsqrtf(var + EPSF) * g1[t] + be1[t];
    const float scale = ln / sm.e.nrms[t];
    const size_t base = (size_t)NTOK*16 + (size_t)i*48 + t*3;
    out[base+0] = sm.e.rawbs[t*3+0] * scale;
    out[base+1] = sm.e.rawbs[t*3+1] * scale;
    out[base+2] = sm.e.rawbs[t*3+2] * scale;
  }
}

extern "C" void kernel_launch(void* const* d_in, const int* in_sizes, int n_in,
                              void* d_out, int out_size, void* d_ws, size_t ws_size,
                              hipStream_t stream) {
  int idx_f0 = -1, idx_f1 = -1, idx_rbf = -1, idx_rhat = -1, idx_mask = -1;
  int wa_i[4], ba_i[4], wb_i[4], bb_i[4], g_i[4];
  int nwa = 0, nba = 0, nwb = 0, nbb = 0, ng = 0;
  for (int k = 0; k < n_in; ++k) {
    const int s = in_sizes[k];
    if      (s == 4194304) idx_rbf  = k;
    else if (s == 786432)  idx_rhat = k;
    else if (s == 262144)  idx_mask = k;
    else if (s == 24576)   idx_f1   = k;
    else if (s == 8192)    { if (idx_f0 < 0) idx_f0 = k; else if (nwb < 4) wb_i[nwb++] = k; }
    else if (s == 512)     { if (nwa < 4) wa_i[nwa++] = k; }
    else if (s == 32)      { if (nba < 4) ba_i[nba++] = k; }
    else if (s == 256)     { if (nbb < 4) bb_i[nbb++] = k; }
    else if (s == 16)      { if (ng  < 4) g_i[ng++]  = k; }
  }
  const bool ok = idx_f0 >= 0 && idx_f1 >= 0 && idx_rbf >= 0 && idx_rhat >= 0 &&
                  idx_mask >= 0 && nwa == 4 && nba == 4 && nwb == 4 && nbb == 4 && ng == 4;
  if (!ok) {
    idx_f0 = 1; idx_f1 = 2; idx_rbf = 3; idx_rhat = 4; idx_mask = 5;
    for (int q = 0; q < 4; ++q) {
      wa_i[q] = 6 + q*4; ba_i[q] = 7 + q*4; wb_i[q] = 8 + q*4; bb_i[q] = 9 + q*4;
      g_i[q] = 22 + q;
    }
  }
  tfn_kernel<<<512, 1024, 0, stream>>>(
      (const float*)d_in[idx_f0],  (const float*)d_in[idx_f1],
      (const float*)d_in[idx_rbf], (const float*)d_in[idx_rhat],
      (const int*)d_in[idx_mask],
      (const float*)d_in[wa_i[0]], (const float*)d_in[ba_i[0]],
      (const float*)d_in[wb_i[0]], (const float*)d_in[bb_i[0]],
      (const float*)d_in[wa_i[1]], (const float*)d_in[ba_i[1]],
      (const float*)d_in[wb_i[1]], (const float*)d_in[bb_i[1]],
      (const float*)d_in[wa_i[2]], (const float*)d_in[ba_i[2]],
      (const float*)d_in[wb_i[2]], (const float*)d_in[bb_i[2]],
      (const float*)d_in[wa_i[3]], (const float*)d_in[ba_i[3]],
      (const float*)d_in[wb_i[3]], (const float*)d_in[bb_i[3]],
      (const float*)d_in[g_i[0]], (const float*)d_in[g_i[1]],
      (const float*)d_in[g_i[2]], (const float*)d_in[g_i[3]],
      (float*)d_out);
}